// Round 11
// baseline (329.581 us; speedup 1.0000x reference)
//
#include <hip/hip_runtime.h>

#define B_ 8
#define N_ 1024
#define C_ 768
#define H_ 6
#define HID_ 3072
#define EPSV 1e-6f
#define SCALE_V 0.125f
#define DPAD 70

typedef unsigned short u16t;
typedef unsigned int u32t;
typedef __attribute__((ext_vector_type(8))) short bf16x8;
typedef __attribute__((ext_vector_type(4))) float f32x4;

__device__ __forceinline__ float b2f(u16t u) {
  union { u32t i; float f; } c; c.i = ((u32t)u) << 16; return c.f;
}
__device__ __forceinline__ u16t f2b(float f) {
  union { float f; u32t i; } c; c.f = f;
  u32t r = c.i + 0x7FFFu + ((c.i >> 16) & 1u);
  return (u16t)(r >> 16);
}
__device__ __forceinline__ float ldval(const float* p) { return *p; }
__device__ __forceinline__ float ldval(const u16t* p) { return b2f(*p); }

// overflow-safe tanh-approx GELU (|err| ~1e-3, << bf16 storage noise)
__device__ __forceinline__ float gelu_f(float v) {
  const float u = v * (0.79788456f + 0.0356774081f * v * v);
  const float e = __expf(2.f * u);
  const float th = 1.f - 2.f / (e + 1.f);
  return 0.5f * v * (1.f + th);
}

// async global->LDS, 16B per lane; LDS dest wave-uniform base + lane*16
__device__ __forceinline__ void gl16(const u16t* g, u16t* l) {
  __builtin_amdgcn_global_load_lds(
      (const __attribute__((address_space(1))) unsigned int*)g,
      (__attribute__((address_space(3))) unsigned int*)l, 16, 0, 0);
}

// bijective XCD-chunked block swizzle (requires nwg % 8 == 0)
__device__ __forceinline__ int xcd_swz() {
  const int gx = gridDim.x, gy = gridDim.y;
  const int nwg = gx * gy * gridDim.z;
  const int h = blockIdx.x + gx * (blockIdx.y + gy * blockIdx.z);
  return (h & 7) * (nwg >> 3) + (h >> 3);
}

// ---------------- fused weight prep: 6x (W[K][N] f32 -> Wt[N][K] bf16) ----
struct W6 {
  const float* w[6];
  u16t* wt[6];
  int K[6]; int N[6];
  int start[7];
};
__global__ __launch_bounds__(256) void wprep_all(W6 d) {
  __shared__ u16t tile[32][40];
  const int bid = blockIdx.x;
  int z = 0;
  while (bid >= d.start[z + 1]) ++z;      // uniform, <=6 iters
  const float* W = d.w[z];
  u16t* Wt = d.wt[z];
  const int K = d.K[z], N = d.N[z];
  const int local = bid - d.start[z];
  const int nb = N >> 5;
  const int n0 = (local % nb) * 32, k0 = (local / nb) * 32;
  const int tx = threadIdx.x & 31, ty = threadIdx.x >> 5;
#pragma unroll
  for (int j = 0; j < 4; ++j) {
    const int k = ty + j * 8;
    tile[k][tx] = f2b(W[(size_t)(k0 + k) * N + n0 + tx]);
  }
  __syncthreads();
#pragma unroll
  for (int j = 0; j < 4; ++j) {
    const int n = ty + j * 8;
    Wt[(size_t)(n0 + n) * K + k0 + tx] = tile[tx][n];
  }
}

// ---------------- fused LN1 (both halves), one wave per row ----------------
__global__ __launch_bounds__(256) void ln1_both_k(
    const float* __restrict__ x,
    const float* __restrict__ gg, const float* __restrict__ gb,
    const float* __restrict__ lg, const float* __restrict__ lb,
    u16t* __restrict__ og, u16t* __restrict__ ol, int rows)
{
  const int wv = threadIdx.x >> 6, lane = threadIdx.x & 63;
  const int row = blockIdx.x * 4 + wv;
  if (row >= rows) return;
  const float* ip = x + (size_t)row * 768;
  float xs[12];
  float s0 = 0.f, ss0 = 0.f, s1 = 0.f, ss1 = 0.f;
#pragma unroll
  for (int c = 0; c < 6; ++c) {
    float v = ip[c * 64 + lane];
    xs[c] = v; s0 += v; ss0 += v * v;
  }
#pragma unroll
  for (int c = 0; c < 6; ++c) {
    float v = ip[384 + c * 64 + lane];
    xs[6 + c] = v; s1 += v; ss1 += v * v;
  }
#pragma unroll
  for (int o = 32; o > 0; o >>= 1) {
    s0 += __shfl_xor(s0, o, 64); ss0 += __shfl_xor(ss0, o, 64);
    s1 += __shfl_xor(s1, o, 64); ss1 += __shfl_xor(ss1, o, 64);
  }
  const float m0 = s0 / 384.f, m1 = s1 / 384.f;
  const float i0 = 1.f / sqrtf(ss0 / 384.f - m0 * m0 + EPSV);
  const float i1 = 1.f / sqrtf(ss1 / 384.f - m1 * m1 + EPSV);
  u16t* o0 = og + (size_t)row * 384;
  u16t* o1 = ol + (size_t)row * 384;
#pragma unroll
  for (int c = 0; c < 6; ++c) {
    const int i = c * 64 + lane;
    o0[i] = f2b((xs[c] - m0) * i0 * gg[i] + gb[i]);
    o1[i] = f2b((xs[6 + c] - m1) * i1 * lg[i] + lb[i]);
  }
}

// ---------------- LayerNorm (LN2): one wave per row ----------------
template<int D, typename TIN>
__global__ __launch_bounds__(256) void ln_kernel(
    const TIN* __restrict__ in, int istride, int icol,
    const float* __restrict__ gam, const float* __restrict__ bet,
    u16t* __restrict__ outp, int rows)
{
  const int wv = threadIdx.x >> 6, lane = threadIdx.x & 63;
  const int row = blockIdx.x * 4 + wv;
  if (row >= rows) return;
  constexpr int NC = D / 64;
  float xs[NC];
  const TIN* ip = in + (size_t)row * istride + icol;
  float s = 0.f, ss = 0.f;
#pragma unroll
  for (int c = 0; c < NC; ++c) {
    float v = ldval(ip + c * 64 + lane);
    xs[c] = v; s += v; ss += v * v;
  }
#pragma unroll
  for (int o = 32; o > 0; o >>= 1) {
    s += __shfl_xor(s, o, 64);
    ss += __shfl_xor(ss, o, 64);
  }
  const float m = s / (float)D;
  const float var = ss / (float)D - m * m;
  const float inv = 1.0f / sqrtf(var + EPSV);
  u16t* op = outp + (size_t)row * D;
#pragma unroll
  for (int c = 0; c < NC; ++c) {
    int i = c * 64 + lane;
    op[i] = f2b((xs[c] - m) * inv * gam[i] + bet[i]);
  }
}

// ---------------- MFMA GEMM, 16x16x32 inner, 2-stage pipelined, XCD-swz ---
// (exact round-8 kernel: 128x128 tile, BK=64, 4 waves, dbuf, vmcnt(8))
__global__ __launch_bounds__(256) void gemm_mfma(
    const u16t* __restrict__ A0, const u16t* __restrict__ A1, int lda,
    const u16t* __restrict__ B0, const u16t* __restrict__ B1, int ldb,
    const float* bias0, const float* bias1,
    const void* res0, const void* res1, int ldr, int res_f32,
    void* out0, void* out1, int ldo, int out_f32,
    int K, int act)
{
  __shared__ u16t As[2][128][64];
  __shared__ u16t Bs[2][128][64];
  const int gx = gridDim.x, gy = gridDim.y;
  int t0f = xcd_swz();
  const int bx = t0f % gx;
  const int tmp = t0f / gx;
  const int by = tmp % gy;
  const int z = tmp / gy;

  const u16t* Aw  = z ? A1 : A0;
  const u16t* Btw = z ? B1 : B0;
  const float* bias = z ? bias1 : bias0;
  const void* res = z ? res1 : res0;
  void* outp = z ? out1 : out0;

  const int t = threadIdx.x;
  const int m0 = by * 128, n0 = bx * 128;
  const int wid = t >> 6, lane = t & 63;
  const int wr = wid >> 1, wc = wid & 1;
  const int lrow = lane & 15, lk = lane >> 4;

  const int srow = lane >> 3;                  // row within 8-row group
  const int scol = ((lane & 7) ^ srow) << 3;   // swizzled k-offset (elems)
  const u16t* aSrc = Aw  + (size_t)(m0 + wid * 32 + srow) * lda + scol;
  const u16t* bSrc = Btw + (size_t)(n0 + wid * 32 + srow) * ldb + scol;

  auto stage = [&](int bufi, int kt_) {
    u16t* aD = &As[bufi][wid * 32][0];
    u16t* bD = &Bs[bufi][wid * 32][0];
#pragma unroll
    for (int i = 0; i < 4; ++i) {
      gl16(aSrc + (size_t)i * 8 * lda + kt_ * 64, aD + i * 8 * 64);
      gl16(bSrc + (size_t)i * 8 * ldb + kt_ * 64, bD + i * 8 * 64);
    }
  };

  f32x4 acc[4][4];
#pragma unroll
  for (int m = 0; m < 4; ++m)
#pragma unroll
    for (int n = 0; n < 4; ++n) acc[m][n] = (f32x4)(0.f);

  const int nt = K >> 6;
  stage(0, 0);
  for (int kt = 0; kt < nt; ++kt) {
    const int cur = kt & 1;
    if (kt + 1 < nt) {
      stage(cur ^ 1, kt + 1);
      asm volatile("s_waitcnt vmcnt(8)" ::: "memory");  // tile kt ready; kt+1 in flight
    } else {
      asm volatile("s_waitcnt vmcnt(0)" ::: "memory");
    }
    __builtin_amdgcn_s_barrier();
    __builtin_amdgcn_sched_barrier(0);
#pragma unroll
    for (int kk = 0; kk < 2; ++kk) {
      bf16x8 aF[4], bF[4];
      const int k8 = kk * 4 + lk;
#pragma unroll
      for (int f = 0; f < 4; ++f) {
        const int ar = wr * 64 + f * 16 + lrow;
        aF[f] = *reinterpret_cast<const bf16x8*>(&As[cur][ar][(k8 ^ (ar & 7)) << 3]);
        const int br = wc * 64 + f * 16 + lrow;
        bF[f] = *reinterpret_cast<const bf16x8*>(&Bs[cur][br][(k8 ^ (br & 7)) << 3]);
      }
#pragma unroll
      for (int m = 0; m < 4; ++m)
#pragma unroll
        for (int n = 0; n < 4; ++n)
          acc[m][n] = __builtin_amdgcn_mfma_f32_16x16x32_bf16(
              aF[m], bF[n], acc[m][n], 0, 0, 0);
    }
    __builtin_amdgcn_s_barrier();   // all reads of buf[cur] done -> overwrite safe
  }

  const int orow0 = (lane >> 4) * 4;
  const int ocol = lane & 15;
#pragma unroll
  for (int m = 0; m < 4; ++m) {
#pragma unroll
    for (int n = 0; n < 4; ++n) {
      const int gn = n0 + wc * 64 + n * 16 + ocol;
      const float bv = bias ? bias[gn] : 0.f;
#pragma unroll
      for (int i = 0; i < 4; ++i) {
        const int gm = m0 + wr * 64 + m * 16 + orow0 + i;
        float v = acc[m][n][i] + bv;
        if (act == 1) v = gelu_f(v);
        if (res) v += res_f32 ? ((const float*)res)[(size_t)gm * ldr + gn]
                              : b2f(((const u16t*)res)[(size_t)gm * ldr + gn]);
        if (out_f32) ((float*)outp)[(size_t)gm * ldo + gn] = v;
        else         ((u16t*)outp)[(size_t)gm * ldo + gn] = f2b(v);
      }
    }
  }
}

// ---------------- 256x256 MFMA GEMM, 8 waves, 4-phase interleave ----------
// 512 threads (2M x 4N waves); per wave 128x64 output = acc[8][4].
// dbuf LDS 128KB. Per K-tile: 4 phases of {2 gl16 (next tile) || ds_read ||
// 16 MFMA in setprio}; one vmcnt(0)+barrier per tile (loads issued ~3
// phases early -> latency hidden). XOR swizzle w/ pre-swizzled source.
__global__ __launch_bounds__(512) void gemm256(
    const u16t* __restrict__ A, int lda,
    const u16t* __restrict__ Bt, int ldb,
    const float* __restrict__ bias,
    const void* __restrict__ res, int ldr, int res_f32,
    void* __restrict__ outp, int ldo, int out_f32,
    int K, int act)
{
  __shared__ u16t As[2][256][64];
  __shared__ u16t Bs[2][256][64];
  const int gx = gridDim.x;
  int tf = xcd_swz();
  const int bx = tf % gx, by = tf / gx;
  const int m0 = by * 256, n0 = bx * 256;
  const int t = threadIdx.x;
  const int wid = t >> 6, lane = t & 63;
  const int wm = wid >> 2, wn = wid & 3;     // 2 x 4 waves
  const int lrow = lane & 15, lk = lane >> 4;

  // staging: wave wid + issue i covers rows {wid*8..wid*8+7} + i*64
  const int srow = lane >> 3;
  const int scol = ((lane & 7) ^ srow) << 3;
  const u16t* aSrc = A  + (size_t)(m0 + wid * 8 + srow) * lda + scol;
  const u16t* bSrc = Bt + (size_t)(n0 + wid * 8 + srow) * ldb + scol;

  f32x4 acc[8][4];
#pragma unroll
  for (int f = 0; f < 8; ++f)
#pragma unroll
    for (int g = 0; g < 4; ++g) acc[f][g] = (f32x4)(0.f);

  const int nt = K >> 6;
  // prologue: full tile 0
#pragma unroll
  for (int i = 0; i < 4; ++i) {
    gl16(aSrc + (size_t)i * 64 * lda, &As[0][i * 64 + wid * 8][0]);
    gl16(bSrc + (size_t)i * 64 * ldb, &Bs[0][i * 64 + wid * 8][0]);
  }
  asm volatile("s_waitcnt vmcnt(0)" ::: "memory");
  __builtin_amdgcn_s_barrier();

  for (int kt = 0; kt < nt; ++kt) {
    const int cur = kt & 1;
    const int nxt = cur ^ 1;
    const bool pf = (kt + 1 < nt);
    const size_t koff = (size_t)(kt + 1) * 64;
    bf16x8 aF[4], bF[4];

#pragma unroll
    for (int kk = 0; kk < 2; ++kk) {
      const int k8 = kk * 4 + lk;
      const int sw = (k8 ^ (lrow & 7)) << 3;     // lane-static per kk
      // ---- phase A (f = 0..3) ----
      if (pf) {
        const int i = kk * 2;
        gl16(aSrc + (size_t)i * 64 * lda + koff, &As[nxt][i * 64 + wid * 8][0]);
        gl16(bSrc + (size_t)i * 64 * ldb + koff, &Bs[nxt][i * 64 + wid * 8][0]);
      }
#pragma unroll
      for (int g = 0; g < 4; ++g)
        bF[g] = *reinterpret_cast<const bf16x8*>(&Bs[cur][wn * 64 + g * 16 + lrow][sw]);
#pragma unroll
      for (int f = 0; f < 4; ++f)
        aF[f] = *reinterpret_cast<const bf16x8*>(&As[cur][wm * 128 + f * 16 + lrow][sw]);
      __builtin_amdgcn_s_setprio(1);
#pragma unroll
      for (int f = 0; f < 4; ++f)
#pragma unroll
        for (int g = 0; g < 4; ++g)
          acc[f][g] = __builtin_amdgcn_mfma_f32_16x16x32_bf16(
              aF[f], bF[g], acc[f][g], 0, 0, 0);
      __builtin_amdgcn_s_setprio(0);
      // ---- phase B (f = 4..7) ----
      if (pf) {
        const int i = kk * 2 + 1;
        gl16(aSrc + (size_t)i * 64 * lda + koff, &As[nxt][i * 64 + wid * 8][0]);
        gl16(bSrc + (size_t)i * 64 * ldb + koff, &Bs[nxt][i * 64 + wid * 8][0]);
      }
#pragma unroll
      for (int f = 0; f < 4; ++f)
        aF[f] = *reinterpret_cast<const bf16x8*>(
            &As[cur][wm * 128 + 64 + f * 16 + lrow][sw]);
      __builtin_amdgcn_s_setprio(1);
#pragma unroll
      for (int f = 0; f < 4; ++f)
#pragma unroll
        for (int g = 0; g < 4; ++g)
          acc[4 + f][g] = __builtin_amdgcn_mfma_f32_16x16x32_bf16(
              aF[f], bF[g], acc[4 + f][g], 0, 0, 0);
      __builtin_amdgcn_s_setprio(0);
    }
    asm volatile("s_waitcnt vmcnt(0)" ::: "memory");
    __builtin_amdgcn_s_barrier();
  }

  const int orow0 = (lane >> 4) * 4;
  const int ocol = lane & 15;
#pragma unroll
  for (int f = 0; f < 8; ++f) {
#pragma unroll
    for (int g = 0; g < 4; ++g) {
      const int gn = n0 + wn * 64 + g * 16 + ocol;
      const float bv = bias ? bias[gn] : 0.f;
#pragma unroll
      for (int i = 0; i < 4; ++i) {
        const int gm = m0 + wm * 128 + f * 16 + orow0 + i;
        float v = acc[f][g][i] + bv;
        if (act == 1) v = gelu_f(v);
        if (res) v += res_f32 ? ((const float*)res)[(size_t)gm * ldr + gn]
                              : b2f(((const u16t*)res)[(size_t)gm * ldr + gn]);
        if (out_f32) ((float*)outp)[(size_t)gm * ldo + gn] = v;
        else         ((u16t*)outp)[(size_t)gm * ldo + gn] = f2b(v);
      }
    }
  }
}

// ---------------- Global attention, MFMA flash, XCD-swz -------------------
__global__ __launch_bounds__(256) void gattn_mfma(
    const u16t* __restrict__ qkv, u16t* __restrict__ outp)
{
  __shared__ u16t Ks[64][DPAD];
  __shared__ u16t Vt[64][DPAD];
  __shared__ u16t Pw[4][16][DPAD];
  const int t = threadIdx.x;
  int tf = xcd_swz();
  const int q0 = (tf % 16) * 64;
  const int h = (tf / 16) % H_;
  const int b = tf / (16 * H_);
  const size_t base = (size_t)b * N_ * 1152 + h * 64;

  const int wid = t >> 6, lane = t & 63;
  const int lc = lane & 15;
  const int lg = lane >> 4;

  bf16x8 qf[2];
  {
    const u16t* qp = qkv + base + (size_t)(q0 + wid * 16 + lc) * 1152 + 8 * lg;
    qf[0] = *reinterpret_cast<const bf16x8*>(qp);
    qf[1] = *reinterpret_cast<const bf16x8*>(qp + 32);
  }

  f32x4 Of[4];
#pragma unroll
  for (int nf = 0; nf < 4; ++nf) Of[nf] = (f32x4)(0.f);
  float m_run[4], l_run[4];
#pragma unroll
  for (int i = 0; i < 4; ++i) { m_run[i] = -INFINITY; l_run[i] = 0.f; }

  const int sj = t >> 2, sd0 = (t & 3) * 16;

  for (int kt = 0; kt < 16; ++kt) {
    __syncthreads();
    {
      const u16t* kp = qkv + base + (size_t)(kt * 64 + sj) * 1152 + 384 + sd0;
      uint4 k0 = *reinterpret_cast<const uint4*>(kp);
      uint4 k1 = *reinterpret_cast<const uint4*>(kp + 8);
      *reinterpret_cast<uint4*>(&Ks[sj][sd0])     = k0;
      *reinterpret_cast<uint4*>(&Ks[sj][sd0 + 8]) = k1;
      const u16t* vp = kp + 384;
      u16t tv[16];
      *reinterpret_cast<uint4*>(tv)     = *reinterpret_cast<const uint4*>(vp);
      *reinterpret_cast<uint4*>(tv + 8) = *reinterpret_cast<const uint4*>(vp + 8);
#pragma unroll
      for (int e = 0; e < 16; ++e) Vt[sd0 + e][sj] = tv[e];
    }
    __syncthreads();

    f32x4 sc[4];
#pragma unroll
    for (int nf = 0; nf < 4; ++nf) sc[nf] = (f32x4)(0.f);
    __builtin_amdgcn_s_setprio(1);
#pragma unroll
    for (int kc = 0; kc < 2; ++kc) {
#pragma unroll
      for (int nf = 0; nf < 4; ++nf) {
        bf16x8 kf = *reinterpret_cast<const bf16x8*>(&Ks[nf * 16 + lc][8 * lg + 32 * kc]);
        sc[nf] = __builtin_amdgcn_mfma_f32_16x16x32_bf16(qf[kc], kf, sc[nf], 0, 0, 0);
      }
    }
    __builtin_amdgcn_s_setprio(0);

#pragma unroll
    for (int i = 0; i < 4; ++i) {
      float s0 = sc[0][i] * SCALE_V, s1 = sc[1][i] * SCALE_V;
      float s2 = sc[2][i] * SCALE_V, s3 = sc[3][i] * SCALE_V;
      float mi = fmaxf(fmaxf(s0, s1), fmaxf(s2, s3));
#pragma unroll
      for (int o = 8; o > 0; o >>= 1) mi = fmaxf(mi, __shfl_xor(mi, o, 64));
      const float nm = fmaxf(m_run[i], mi);
      const float alpha = __expf(m_run[i] - nm);
      m_run[i] = nm;
      float p0 = __expf(s0 - nm), p1 = __expf(s1 - nm);
      float p2 = __expf(s2 - nm), p3 = __expf(s3 - nm);
      const int prow = lg * 4 + i;
      Pw[wid][prow][lc]      = f2b(p0);
      Pw[wid][prow][16 + lc] = f2b(p1);
      Pw[wid][prow][32 + lc] = f2b(p2);
      Pw[wid][prow][48 + lc] = f2b(p3);
      float ls = p0 + p1 + p2 + p3;
#pragma unroll
      for (int o = 8; o > 0; o >>= 1) ls += __shfl_xor(ls, o, 64);
      l_run[i] = l_run[i] * alpha + ls;
#pragma unroll
      for (int nf = 0; nf < 4; ++nf) Of[nf][i] *= alpha;
    }

    __builtin_amdgcn_s_setprio(1);
#pragma unroll
    for (int kc = 0; kc < 2; ++kc) {
      bf16x8 pf = *reinterpret_cast<const bf16x8*>(&Pw[wid][lc][8 * lg + 32 * kc]);
#pragma unroll
      for (int nf = 0; nf < 4; ++nf) {
        bf16x8 vf = *reinterpret_cast<const bf16x8*>(&Vt[nf * 16 + lc][8 * lg + 32 * kc]);
        Of[nf] = __builtin_amdgcn_mfma_f32_16x16x32_bf16(pf, vf, Of[nf], 0, 0, 0);
      }
    }
    __builtin_amdgcn_s_setprio(0);
  }

#pragma unroll
  for (int i = 0; i < 4; ++i) {
    const float inv = 1.f / l_run[i];
    const size_t row = (size_t)b * N_ + q0 + wid * 16 + lg * 4 + i;
#pragma unroll
    for (int nf = 0; nf < 4; ++nf)
      outp[row * 384 + h * 64 + nf * 16 + lc] = f2b(Of[nf][i] * inv);
  }
}

// ---------------- Local (band=1) attention ----------------
__global__ __launch_bounds__(256) void lattn_k(
    const u16t* __restrict__ qkv, u16t* __restrict__ outp)
{
  const int tg = blockIdx.x * 256 + threadIdx.x;
  if (tg >= B_ * N_ * H_) return;
  const int h = tg % H_;
  const int n = (tg / H_) % N_;
  const int b = tg / (H_ * N_);
  const size_t qb = ((size_t)b * N_ + n) * 1152 + h * 64;

  float q[64];
#pragma unroll
  for (int dc = 0; dc < 8; ++dc) {
    u16t tq[8];
    *reinterpret_cast<uint4*>(tq) = *reinterpret_cast<const uint4*>(qkv + qb + dc * 8);
#pragma unroll
    for (int s2 = 0; s2 < 8; ++s2) q[dc * 8 + s2] = b2f(tq[s2]);
  }

  const int jm = (n > 0) ? n - 1 : 0;
  const int jp = (n < N_ - 1) ? n + 1 : N_ - 1;
  const size_t kb0 = ((size_t)b * N_ + jm) * 1152 + 384 + h * 64;
  const size_t kb1 = ((size_t)b * N_ + n ) * 1152 + 384 + h * 64;
  const size_t kb2 = ((size_t)b * N_ + jp) * 1152 + 384 + h * 64;

  float s0 = 0.f, s1 = 0.f, s2v = 0.f;
#pragma unroll
  for (int dc = 0; dc < 8; ++dc) {
    u16t t0[8], t1[8], t2[8];
    *reinterpret_cast<uint4*>(t0) = *reinterpret_cast<const uint4*>(qkv + kb0 + dc * 8);
    *reinterpret_cast<uint4*>(t1) = *reinterpret_cast<const uint4*>(qkv + kb1 + dc * 8);
    *reinterpret_cast<uint4*>(t2) = *reinterpret_cast<const uint4*>(qkv + kb2 + dc * 8);
#pragma unroll
    for (int s = 0; s < 8; ++s) {
      float qv = q[dc * 8 + s];
      s0 = fmaf(qv, b2f(t0[s]), s0);
      s1 = fmaf(qv, b2f(t1[s]), s1);
      s2v = fmaf(qv, b2f(t2[s]), s2v);
    }
  }
  s0 = (n > 0)      ? s0 * SCALE_V : -1e30f;
  s1 = s1 * SCALE_V;
  s2v = (n < N_ - 1) ? s2v * SCALE_V : -1e30f;
  float m = fmaxf(s1, fmaxf(s0, s2v));
  float p0 = __expf(s0 - m), p1 = __expf(s1 - m), p2 = __expf(s2v - m);
  float inv = 1.f / (p0 + p1 + p2);
  p0 *= inv; p1 *= inv; p2 *= inv;

  const size_t vb0 = kb0 + 384, vb1 = kb1 + 384, vb2 = kb2 + 384;
  u16t* op = outp + ((size_t)b * N_ + n) * 384 + h * 64;
#pragma unroll
  for (int dc = 0; dc < 8; ++dc) {
    u16t t0[8], t1[8], t2[8], ot[8];
    *reinterpret_cast<uint4*>(t0) = *reinterpret_cast<const uint4*>(qkv + vb0 + dc * 8);
    *reinterpret_cast<uint4*>(t1) = *reinterpret_cast<const uint4*>(qkv + vb1 + dc * 8);
    *reinterpret_cast<uint4*>(t2) = *reinterpret_cast<const uint4*>(qkv + vb2 + dc * 8);
#pragma unroll
    for (int s = 0; s < 8; ++s)
      ot[s] = f2b(p0 * b2f(t0[s]) + p1 * b2f(t1[s]) + p2 * b2f(t2[s]));
    *reinterpret_cast<uint4*>(op + dc * 8) = *reinterpret_cast<uint4*>(ot);
  }
}

// ---------------- launch ----------------
extern "C" void kernel_launch(void* const* d_in, const int* in_sizes, int n_in,
                              void* d_out, int out_size, void* d_ws, size_t ws_size,
                              hipStream_t stream) {
  const float* x        = (const float*)d_in[0];
  const float* ln1_g    = (const float*)d_in[1];
  const float* ln1_b    = (const float*)d_in[2];
  const float* ln1l_g   = (const float*)d_in[3];
  const float* ln1l_b   = (const float*)d_in[4];
  const float* g_qkv_w  = (const float*)d_in[5];
  const float* g_proj_w = (const float*)d_in[6];
  const float* g_proj_b = (const float*)d_in[7];
  const float* l_qkv_w  = (const float*)d_in[8];
  const float* l_proj_w = (const float*)d_in[9];
  const float* l_proj_b = (const float*)d_in[10];
  const float* ln2_g    = (const float*)d_in[11];
  const float* ln2_b    = (const float*)d_in[12];
  const float* fc1_w    = (const float*)d_in[13];
  const float* fc1_b    = (const float*)d_in[14];
  const float* fc2_w    = (const float*)d_in[15];
  const float* fc2_b    = (const float*)d_in[16];
  float* out = (float*)d_out;
  u16t* ws = (u16t*)d_ws;

  u16t* gqkv_wt = ws + 0;          // [1152][384]
  u16t* lqkv_wt = ws + 442368;     // [1152][384]
  u16t* gproj_wt= ws + 884736;     // [384][384]
  u16t* lproj_wt= ws + 1032192;    // [384][384]
  u16t* fc1_wt  = ws + 1179648;    // [3072][768]
  u16t* fc2_wt  = ws + 3538944;    // [768][3072]
  u16t* lng  = ws + 5898240;       // 8192x384
  u16t* lnl  = ws + 9043968;       // 8192x384
  u16t* qkvg = ws + 12189696;      // 8192x1152
  u16t* qkvl = ws + 21626880;      // 8192x1152
  u16t* attg = lng;
  u16t* attl = lnl;
  u16t* x1   = ws + 12189696;      // aliases qkvg (dead by proj)
  u16t* ln2o = ws + 5898240;       // aliases lng/lnl
  u16t* hbuf = ws + 18481152;      // 8192x3072

  const int rows = B_ * N_;

  W6 w6;
  w6.w[0] = g_qkv_w;  w6.wt[0] = gqkv_wt;  w6.K[0] = 384;  w6.N[0] = 1152;
  w6.w[1] = l_qkv_w;  w6.wt[1] = lqkv_wt;  w6.K[1] = 384;  w6.N[1] = 1152;
  w6.w[2] = g_proj_w; w6.wt[2] = gproj_wt; w6.K[2] = 384;  w6.N[2] = 384;
  w6.w[3] = l_proj_w; w6.wt[3] = lproj_wt; w6.K[3] = 384;  w6.N[3] = 384;
  w6.w[4] = fc1_w;    w6.wt[4] = fc1_wt;   w6.K[4] = 768;  w6.N[4] = 3072;
  w6.w[5] = fc2_w;    w6.wt[5] = fc2_wt;   w6.K[5] = 3072; w6.N[5] = 768;
  int acc0 = 0;
  for (int i = 0; i < 6; ++i) {
    w6.start[i] = acc0;
    acc0 += (w6.N[i] / 32) * (w6.K[i] / 32);
  }
  w6.start[6] = acc0;   // 5760
  wprep_all<<<dim3(acc0), 256, 0, stream>>>(w6);

  ln1_both_k<<<dim3(2048), 256, 0, stream>>>(
      x, ln1_g, ln1_b, ln1l_g, ln1l_b, lng, lnl, rows);

  // qkv (both branches, z-merged)
  gemm_mfma<<<dim3(9, 64, 2), 256, 0, stream>>>(
      lng, lnl, 384, gqkv_wt, lqkv_wt, 384,
      nullptr, nullptr, nullptr, nullptr, 0, 0,
      qkvg, qkvl, 1152, 0, 384, 0);

  gattn_mfma<<<dim3(16, H_, B_), 256, 0, stream>>>(qkvg, attg);
  lattn_k<<<dim3(192), 256, 0, stream>>>(qkvl, attl);

  // proj (both branches, z-merged), residual from x (f32), out bf16 x1
  gemm_mfma<<<dim3(3, 64, 2), 256, 0, stream>>>(
      attg, attl, 384, gproj_wt, lproj_wt, 384,
      g_proj_b, l_proj_b, x, x + 384, 768, 1,
      x1, x1 + 384, 768, 0, 384, 0);

  ln_kernel<768, u16t><<<dim3(2048), 256, 0, stream>>>(x1, 768, 0, ln2_g, ln2_b, ln2o, rows);

  // fc1: 256x256 8-wave kernel (N=3072 divisible by 256; grid 384 %8==0)
  gemm256<<<dim3(12, 32), 512, 0, stream>>>(
      ln2o, 768, fc1_wt, 768, fc1_b, nullptr, 0, 0,
      hbuf, 3072, 0, 768, 1);

  gemm_mfma<<<dim3(6, 64, 1), 256, 0, stream>>>(
      hbuf, hbuf, 3072, fc2_wt, fc2_wt, 3072,
      fc2_b, fc2_b, x1, x1, 768, 0,
      out, out, 768, 1, 3072, 0);
}

// Round 12
// 270.270 us; speedup vs baseline: 1.2195x; 1.2195x over previous
//
#include <hip/hip_runtime.h>

#define B_ 8
#define N_ 1024
#define C_ 768
#define H_ 6
#define HID_ 3072
#define EPSV 1e-6f
#define SCALE_V 0.125f
#define DPAD 70

typedef unsigned short u16t;
typedef unsigned int u32t;
typedef __attribute__((ext_vector_type(8))) short bf16x8;
typedef __attribute__((ext_vector_type(4))) float f32x4;

__device__ __forceinline__ float b2f(u16t u) {
  union { u32t i; float f; } c; c.i = ((u32t)u) << 16; return c.f;
}
__device__ __forceinline__ u16t f2b(float f) {
  union { float f; u32t i; } c; c.f = f;
  u32t r = c.i + 0x7FFFu + ((c.i >> 16) & 1u);
  return (u16t)(r >> 16);
}
__device__ __forceinline__ float ldval(const float* p) { return *p; }
__device__ __forceinline__ float ldval(const u16t* p) { return b2f(*p); }

// overflow-safe tanh-approx GELU (|err| ~1e-3, << bf16 storage noise)
__device__ __forceinline__ float gelu_f(float v) {
  const float u = v * (0.79788456f + 0.0356774081f * v * v);
  const float e = __expf(2.f * u);
  const float th = 1.f - 2.f / (e + 1.f);
  return 0.5f * v * (1.f + th);
}

// async global->LDS, 16B per lane; LDS dest wave-uniform base + lane*16
__device__ __forceinline__ void gl16(const u16t* g, u16t* l) {
  __builtin_amdgcn_global_load_lds(
      (const __attribute__((address_space(1))) unsigned int*)g,
      (__attribute__((address_space(3))) unsigned int*)l, 16, 0, 0);
}

// bijective XCD-chunked block swizzle (requires nwg % 8 == 0)
__device__ __forceinline__ int xcd_swz() {
  const int gx = gridDim.x, gy = gridDim.y;
  const int nwg = gx * gy * gridDim.z;
  const int h = blockIdx.x + gx * (blockIdx.y + gy * blockIdx.z);
  return (h & 7) * (nwg >> 3) + (h >> 3);
}

// ---------------- fused weight prep: 6x (W[K][N] f32 -> Wt[N][K] bf16) ----
struct W6 {
  const float* w[6];
  u16t* wt[6];
  int K[6]; int N[6];
  int start[7];
};
__global__ __launch_bounds__(256) void wprep_all(W6 d) {
  __shared__ u16t tile[32][40];
  const int bid = blockIdx.x;
  int z = 0;
  while (bid >= d.start[z + 1]) ++z;      // uniform, <=6 iters
  const float* W = d.w[z];
  u16t* Wt = d.wt[z];
  const int K = d.K[z], N = d.N[z];
  const int local = bid - d.start[z];
  const int nb = N >> 5;
  const int n0 = (local % nb) * 32, k0 = (local / nb) * 32;
  const int tx = threadIdx.x & 31, ty = threadIdx.x >> 5;
#pragma unroll
  for (int j = 0; j < 4; ++j) {
    const int k = ty + j * 8;
    tile[k][tx] = f2b(W[(size_t)(k0 + k) * N + n0 + tx]);
  }
  __syncthreads();
#pragma unroll
  for (int j = 0; j < 4; ++j) {
    const int n = ty + j * 8;
    Wt[(size_t)(n0 + n) * K + k0 + tx] = tile[tx][n];
  }
}

// ---------------- fused LN1 (both halves), one wave per row ----------------
__global__ __launch_bounds__(256) void ln1_both_k(
    const float* __restrict__ x,
    const float* __restrict__ gg, const float* __restrict__ gb,
    const float* __restrict__ lg, const float* __restrict__ lb,
    u16t* __restrict__ og, u16t* __restrict__ ol, int rows)
{
  const int wv = threadIdx.x >> 6, lane = threadIdx.x & 63;
  const int row = blockIdx.x * 4 + wv;
  if (row >= rows) return;
  const float* ip = x + (size_t)row * 768;
  float xs[12];
  float s0 = 0.f, ss0 = 0.f, s1 = 0.f, ss1 = 0.f;
#pragma unroll
  for (int c = 0; c < 6; ++c) {
    float v = ip[c * 64 + lane];
    xs[c] = v; s0 += v; ss0 += v * v;
  }
#pragma unroll
  for (int c = 0; c < 6; ++c) {
    float v = ip[384 + c * 64 + lane];
    xs[6 + c] = v; s1 += v; ss1 += v * v;
  }
#pragma unroll
  for (int o = 32; o > 0; o >>= 1) {
    s0 += __shfl_xor(s0, o, 64); ss0 += __shfl_xor(ss0, o, 64);
    s1 += __shfl_xor(s1, o, 64); ss1 += __shfl_xor(ss1, o, 64);
  }
  const float m0 = s0 / 384.f, m1 = s1 / 384.f;
  const float i0 = 1.f / sqrtf(ss0 / 384.f - m0 * m0 + EPSV);
  const float i1 = 1.f / sqrtf(ss1 / 384.f - m1 * m1 + EPSV);
  u16t* o0 = og + (size_t)row * 384;
  u16t* o1 = ol + (size_t)row * 384;
#pragma unroll
  for (int c = 0; c < 6; ++c) {
    const int i = c * 64 + lane;
    o0[i] = f2b((xs[c] - m0) * i0 * gg[i] + gb[i]);
    o1[i] = f2b((xs[6 + c] - m1) * i1 * lg[i] + lb[i]);
  }
}

// ---------------- LayerNorm (LN2): one wave per row ----------------
template<int D, typename TIN>
__global__ __launch_bounds__(256) void ln_kernel(
    const TIN* __restrict__ in, int istride, int icol,
    const float* __restrict__ gam, const float* __restrict__ bet,
    u16t* __restrict__ outp, int rows)
{
  const int wv = threadIdx.x >> 6, lane = threadIdx.x & 63;
  const int row = blockIdx.x * 4 + wv;
  if (row >= rows) return;
  constexpr int NC = D / 64;
  float xs[NC];
  const TIN* ip = in + (size_t)row * istride + icol;
  float s = 0.f, ss = 0.f;
#pragma unroll
  for (int c = 0; c < NC; ++c) {
    float v = ldval(ip + c * 64 + lane);
    xs[c] = v; s += v; ss += v * v;
  }
#pragma unroll
  for (int o = 32; o > 0; o >>= 1) {
    s += __shfl_xor(s, o, 64);
    ss += __shfl_xor(ss, o, 64);
  }
  const float m = s / (float)D;
  const float var = ss / (float)D - m * m;
  const float inv = 1.0f / sqrtf(var + EPSV);
  u16t* op = outp + (size_t)row * D;
#pragma unroll
  for (int c = 0; c < NC; ++c) {
    int i = c * 64 + lane;
    op[i] = f2b((xs[c] - m) * inv * gam[i] + bet[i]);
  }
}

// ---------------- MFMA GEMM, 16x16x32 inner, 2-stage pipelined, XCD-swz ---
// round-8 structure: 128x128 tile, BK=64, 4 waves, dbuf, vmcnt(8).
// bf16-out epilogue: stage C in LDS (aliases dead As/Bs pool), then
// coalesced uint4 stores (replaces 64 scalar 2B stores/thread).
__global__ __launch_bounds__(256) void gemm_mfma(
    const u16t* __restrict__ A0, const u16t* __restrict__ A1, int lda,
    const u16t* __restrict__ B0, const u16t* __restrict__ B1, int ldb,
    const float* bias0, const float* bias1,
    const void* res0, const void* res1, int ldr, int res_f32,
    void* out0, void* out1, int ldo, int out_f32,
    int K, int act)
{
  __shared__ u16t pool[32768];   // 64KB: As | Bs; reused as Cs in epilogue
  u16t (*As)[64] = reinterpret_cast<u16t(*)[64]>(pool);           // [256][64]
  u16t (*Bs)[64] = reinterpret_cast<u16t(*)[64]>(pool + 16384);   // [256][64]
  const int gx = gridDim.x, gy = gridDim.y;
  int t0f = xcd_swz();
  const int bx = t0f % gx;
  const int tmp = t0f / gx;
  const int by = tmp % gy;
  const int z = tmp / gy;

  const u16t* Aw  = z ? A1 : A0;
  const u16t* Btw = z ? B1 : B0;
  const float* bias = z ? bias1 : bias0;
  const void* res = z ? res1 : res0;
  void* outp = z ? out1 : out0;

  const int t = threadIdx.x;
  const int m0 = by * 128, n0 = bx * 128;
  const int wid = t >> 6, lane = t & 63;
  const int wr = wid >> 1, wc = wid & 1;
  const int lrow = lane & 15, lk = lane >> 4;

  const int srow = lane >> 3;                  // row within 8-row group
  const int scol = ((lane & 7) ^ srow) << 3;   // swizzled k-offset (elems)
  const u16t* aSrc = Aw  + (size_t)(m0 + wid * 32 + srow) * lda + scol;
  const u16t* bSrc = Btw + (size_t)(n0 + wid * 32 + srow) * ldb + scol;

  auto stage = [&](int bufi, int kt_) {
    u16t* aD = &As[bufi * 128 + wid * 32][0];
    u16t* bD = &Bs[bufi * 128 + wid * 32][0];
#pragma unroll
    for (int i = 0; i < 4; ++i) {
      gl16(aSrc + (size_t)i * 8 * lda + kt_ * 64, aD + i * 8 * 64);
      gl16(bSrc + (size_t)i * 8 * ldb + kt_ * 64, bD + i * 8 * 64);
    }
  };

  f32x4 acc[4][4];
#pragma unroll
  for (int m = 0; m < 4; ++m)
#pragma unroll
    for (int n = 0; n < 4; ++n) acc[m][n] = (f32x4)(0.f);

  const int nt = K >> 6;
  stage(0, 0);
  for (int kt = 0; kt < nt; ++kt) {
    const int cur = kt & 1;
    if (kt + 1 < nt) {
      stage(cur ^ 1, kt + 1);
      asm volatile("s_waitcnt vmcnt(8)" ::: "memory");  // tile kt ready; kt+1 in flight
    } else {
      asm volatile("s_waitcnt vmcnt(0)" ::: "memory");
    }
    __builtin_amdgcn_s_barrier();
    __builtin_amdgcn_sched_barrier(0);
#pragma unroll
    for (int kk = 0; kk < 2; ++kk) {
      bf16x8 aF[4], bF[4];
      const int k8 = kk * 4 + lk;
#pragma unroll
      for (int f = 0; f < 4; ++f) {
        const int ar = wr * 64 + f * 16 + lrow;
        aF[f] = *reinterpret_cast<const bf16x8*>(&As[cur * 128 + ar][(k8 ^ (ar & 7)) << 3]);
        const int br = wc * 64 + f * 16 + lrow;
        bF[f] = *reinterpret_cast<const bf16x8*>(&Bs[cur * 128 + br][(k8 ^ (br & 7)) << 3]);
      }
#pragma unroll
      for (int m = 0; m < 4; ++m)
#pragma unroll
        for (int n = 0; n < 4; ++n)
          acc[m][n] = __builtin_amdgcn_mfma_f32_16x16x32_bf16(
              aF[m], bF[n], acc[m][n], 0, 0, 0);
    }
    __builtin_amdgcn_s_barrier();   // all reads of buf[cur] done -> overwrite safe
  }

  const int orow0 = (lane >> 4) * 4;
  const int ocol = lane & 15;
  if (out_f32) {
#pragma unroll
    for (int m = 0; m < 4; ++m) {
#pragma unroll
      for (int n = 0; n < 4; ++n) {
        const int gn = n0 + wc * 64 + n * 16 + ocol;
        const float bv = bias ? bias[gn] : 0.f;
#pragma unroll
        for (int i = 0; i < 4; ++i) {
          const int gm = m0 + wr * 64 + m * 16 + orow0 + i;
          float v = acc[m][n][i] + bv;
          if (act == 1) v = gelu_f(v);
          if (res) v += res_f32 ? ((const float*)res)[(size_t)gm * ldr + gn]
                                : b2f(((const u16t*)res)[(size_t)gm * ldr + gn]);
          ((float*)outp)[(size_t)gm * ldo + gn] = v;
        }
      }
    }
  } else {
    // staged bf16 epilogue: pool (As/Bs) is dead after the final barrier
    u16t (*Cs)[136] = reinterpret_cast<u16t(*)[136]>(pool);   // 128x136 = 34.8KB
#pragma unroll
    for (int m = 0; m < 4; ++m) {
#pragma unroll
      for (int n = 0; n < 4; ++n) {
        const int lc2 = wc * 64 + n * 16 + ocol;
        const int gn = n0 + lc2;
        const float bv = bias ? bias[gn] : 0.f;
#pragma unroll
        for (int i = 0; i < 4; ++i) {
          const int lr = wr * 64 + m * 16 + orow0 + i;
          float v = acc[m][n][i] + bv;
          if (act == 1) v = gelu_f(v);
          if (res) v += res_f32 ? ((const float*)res)[(size_t)(m0 + lr) * ldr + gn]
                                : b2f(((const u16t*)res)[(size_t)(m0 + lr) * ldr + gn]);
          Cs[lr][lc2] = f2b(v);
        }
      }
    }
    __syncthreads();
    u16t* ou = (u16t*)outp;
#pragma unroll
    for (int j = 0; j < 8; ++j) {
      const int c = j * 256 + t;        // 0..2047 chunks of 8 u16
      const int r = c >> 4, ch = (c & 15) * 8;
      *reinterpret_cast<uint4*>(ou + (size_t)(m0 + r) * ldo + n0 + ch) =
          *reinterpret_cast<const uint4*>(&Cs[r][ch]);
    }
  }
}

// ---------------- Fused attention: gattn (blocks 0..767) + lattn (768..959)
__global__ __launch_bounds__(256) void attn_both(
    const u16t* __restrict__ qkvg, const u16t* __restrict__ qkvl,
    u16t* __restrict__ og, u16t* __restrict__ ol)
{
  __shared__ u16t Ks[64][DPAD];
  __shared__ u16t Vt[64][DPAD];
  __shared__ u16t Pw[4][16][DPAD];
  const int t = threadIdx.x;
  const int bid = blockIdx.x;

  if (bid < 768) {
    // ---- global attention (MFMA flash), XCD-swizzled over its 768 blocks
    const int tf = (bid & 7) * 96 + (bid >> 3);
    const int q0 = (tf % 16) * 64;
    const int h = (tf / 16) % H_;
    const int b = tf / (16 * H_);
    const size_t base = (size_t)b * N_ * 1152 + h * 64;

    const int wid = t >> 6, lane = t & 63;
    const int lc = lane & 15;
    const int lg = lane >> 4;

    bf16x8 qf[2];
    {
      const u16t* qp = qkvg + base + (size_t)(q0 + wid * 16 + lc) * 1152 + 8 * lg;
      qf[0] = *reinterpret_cast<const bf16x8*>(qp);
      qf[1] = *reinterpret_cast<const bf16x8*>(qp + 32);
    }

    f32x4 Of[4];
#pragma unroll
    for (int nf = 0; nf < 4; ++nf) Of[nf] = (f32x4)(0.f);
    float m_run[4], l_run[4];
#pragma unroll
    for (int i = 0; i < 4; ++i) { m_run[i] = -INFINITY; l_run[i] = 0.f; }

    const int sj = t >> 2, sd0 = (t & 3) * 16;

    for (int kt = 0; kt < 16; ++kt) {
      __syncthreads();
      {
        const u16t* kp = qkvg + base + (size_t)(kt * 64 + sj) * 1152 + 384 + sd0;
        uint4 k0 = *reinterpret_cast<const uint4*>(kp);
        uint4 k1 = *reinterpret_cast<const uint4*>(kp + 8);
        *reinterpret_cast<uint4*>(&Ks[sj][sd0])     = k0;
        *reinterpret_cast<uint4*>(&Ks[sj][sd0 + 8]) = k1;
        const u16t* vp = kp + 384;
        u16t tv[16];
        *reinterpret_cast<uint4*>(tv)     = *reinterpret_cast<const uint4*>(vp);
        *reinterpret_cast<uint4*>(tv + 8) = *reinterpret_cast<const uint4*>(vp + 8);
#pragma unroll
        for (int e = 0; e < 16; ++e) Vt[sd0 + e][sj] = tv[e];
      }
      __syncthreads();

      f32x4 sc[4];
#pragma unroll
      for (int nf = 0; nf < 4; ++nf) sc[nf] = (f32x4)(0.f);
      __builtin_amdgcn_s_setprio(1);
#pragma unroll
      for (int kc = 0; kc < 2; ++kc) {
#pragma unroll
        for (int nf = 0; nf < 4; ++nf) {
          bf16x8 kf = *reinterpret_cast<const bf16x8*>(&Ks[nf * 16 + lc][8 * lg + 32 * kc]);
          sc[nf] = __builtin_amdgcn_mfma_f32_16x16x32_bf16(qf[kc], kf, sc[nf], 0, 0, 0);
        }
      }
      __builtin_amdgcn_s_setprio(0);

#pragma unroll
      for (int i = 0; i < 4; ++i) {
        float s0 = sc[0][i] * SCALE_V, s1 = sc[1][i] * SCALE_V;
        float s2 = sc[2][i] * SCALE_V, s3 = sc[3][i] * SCALE_V;
        float mi = fmaxf(fmaxf(s0, s1), fmaxf(s2, s3));
#pragma unroll
        for (int o = 8; o > 0; o >>= 1) mi = fmaxf(mi, __shfl_xor(mi, o, 64));
        const float nm = fmaxf(m_run[i], mi);
        const float alpha = __expf(m_run[i] - nm);
        m_run[i] = nm;
        float p0 = __expf(s0 - nm), p1 = __expf(s1 - nm);
        float p2 = __expf(s2 - nm), p3 = __expf(s3 - nm);
        const int prow = lg * 4 + i;
        Pw[wid][prow][lc]      = f2b(p0);
        Pw[wid][prow][16 + lc] = f2b(p1);
        Pw[wid][prow][32 + lc] = f2b(p2);
        Pw[wid][prow][48 + lc] = f2b(p3);
        float ls = p0 + p1 + p2 + p3;
#pragma unroll
        for (int o = 8; o > 0; o >>= 1) ls += __shfl_xor(ls, o, 64);
        l_run[i] = l_run[i] * alpha + ls;
#pragma unroll
        for (int nf = 0; nf < 4; ++nf) Of[nf][i] *= alpha;
      }

      __builtin_amdgcn_s_setprio(1);
#pragma unroll
      for (int kc = 0; kc < 2; ++kc) {
        bf16x8 pf = *reinterpret_cast<const bf16x8*>(&Pw[wid][lc][8 * lg + 32 * kc]);
#pragma unroll
        for (int nf = 0; nf < 4; ++nf) {
          bf16x8 vf = *reinterpret_cast<const bf16x8*>(&Vt[nf * 16 + lc][8 * lg + 32 * kc]);
          Of[nf] = __builtin_amdgcn_mfma_f32_16x16x32_bf16(pf, vf, Of[nf], 0, 0, 0);
        }
      }
      __builtin_amdgcn_s_setprio(0);
    }

#pragma unroll
    for (int i = 0; i < 4; ++i) {
      const float inv = 1.f / l_run[i];
      const size_t row = (size_t)b * N_ + q0 + wid * 16 + lg * 4 + i;
#pragma unroll
      for (int nf = 0; nf < 4; ++nf)
        og[row * 384 + h * 64 + nf * 16 + lc] = f2b(Of[nf][i] * inv);
    }
  } else {
    // ---- local (band=1) attention: thread per (b,n,h)
    const int tg = (bid - 768) * 256 + t;
    const int h = tg % H_;
    const int n = (tg / H_) % N_;
    const int b = tg / (H_ * N_);
    const size_t qb = ((size_t)b * N_ + n) * 1152 + h * 64;

    float q[64];
#pragma unroll
    for (int dc = 0; dc < 8; ++dc) {
      u16t tq[8];
      *reinterpret_cast<uint4*>(tq) = *reinterpret_cast<const uint4*>(qkvl + qb + dc * 8);
#pragma unroll
      for (int s2 = 0; s2 < 8; ++s2) q[dc * 8 + s2] = b2f(tq[s2]);
    }

    const int jm = (n > 0) ? n - 1 : 0;
    const int jp = (n < N_ - 1) ? n + 1 : N_ - 1;
    const size_t kb0 = ((size_t)b * N_ + jm) * 1152 + 384 + h * 64;
    const size_t kb1 = ((size_t)b * N_ + n ) * 1152 + 384 + h * 64;
    const size_t kb2 = ((size_t)b * N_ + jp) * 1152 + 384 + h * 64;

    float s0 = 0.f, s1 = 0.f, s2v = 0.f;
#pragma unroll
    for (int dc = 0; dc < 8; ++dc) {
      u16t t0[8], t1[8], t2[8];
      *reinterpret_cast<uint4*>(t0) = *reinterpret_cast<const uint4*>(qkvl + kb0 + dc * 8);
      *reinterpret_cast<uint4*>(t1) = *reinterpret_cast<const uint4*>(qkvl + kb1 + dc * 8);
      *reinterpret_cast<uint4*>(t2) = *reinterpret_cast<const uint4*>(qkvl + kb2 + dc * 8);
#pragma unroll
      for (int s = 0; s < 8; ++s) {
        float qv = q[dc * 8 + s];
        s0 = fmaf(qv, b2f(t0[s]), s0);
        s1 = fmaf(qv, b2f(t1[s]), s1);
        s2v = fmaf(qv, b2f(t2[s]), s2v);
      }
    }
    s0 = (n > 0)      ? s0 * SCALE_V : -1e30f;
    s1 = s1 * SCALE_V;
    s2v = (n < N_ - 1) ? s2v * SCALE_V : -1e30f;
    float m = fmaxf(s1, fmaxf(s0, s2v));
    float p0 = __expf(s0 - m), p1 = __expf(s1 - m), p2 = __expf(s2v - m);
    float inv = 1.f / (p0 + p1 + p2);
    p0 *= inv; p1 *= inv; p2 *= inv;

    const size_t vb0 = kb0 + 384, vb1 = kb1 + 384, vb2 = kb2 + 384;
    u16t* op = ol + ((size_t)b * N_ + n) * 384 + h * 64;
#pragma unroll
    for (int dc = 0; dc < 8; ++dc) {
      u16t t0[8], t1[8], t2[8], ot[8];
      *reinterpret_cast<uint4*>(t0) = *reinterpret_cast<const uint4*>(qkvl + vb0 + dc * 8);
      *reinterpret_cast<uint4*>(t1) = *reinterpret_cast<const uint4*>(qkvl + vb1 + dc * 8);
      *reinterpret_cast<uint4*>(t2) = *reinterpret_cast<const uint4*>(qkvl + vb2 + dc * 8);
#pragma unroll
      for (int s = 0; s < 8; ++s)
        ot[s] = f2b(p0 * b2f(t0[s]) + p1 * b2f(t1[s]) + p2 * b2f(t2[s]));
      *reinterpret_cast<uint4*>(op + dc * 8) = *reinterpret_cast<uint4*>(ot);
    }
  }
}

// ---------------- launch ----------------
extern "C" void kernel_launch(void* const* d_in, const int* in_sizes, int n_in,
                              void* d_out, int out_size, void* d_ws, size_t ws_size,
                              hipStream_t stream) {
  const float* x        = (const float*)d_in[0];
  const float* ln1_g    = (const float*)d_in[1];
  const float* ln1_b    = (const float*)d_in[2];
  const float* ln1l_g   = (const float*)d_in[3];
  const float* ln1l_b   = (const float*)d_in[4];
  const float* g_qkv_w  = (const float*)d_in[5];
  const float* g_proj_w = (const float*)d_in[6];
  const float* g_proj_b = (const float*)d_in[7];
  const float* l_qkv_w  = (const float*)d_in[8];
  const float* l_proj_w = (const float*)d_in[9];
  const float* l_proj_b = (const float*)d_in[10];
  const float* ln2_g    = (const float*)d_in[11];
  const float* ln2_b    = (const float*)d_in[12];
  const float* fc1_w    = (const float*)d_in[13];
  const float* fc1_b    = (const float*)d_in[14];
  const float* fc2_w    = (const float*)d_in[15];
  const float* fc2_b    = (const float*)d_in[16];
  float* out = (float*)d_out;
  u16t* ws = (u16t*)d_ws;

  u16t* gqkv_wt = ws + 0;          // [1152][384]
  u16t* lqkv_wt = ws + 442368;     // [1152][384]
  u16t* gproj_wt= ws + 884736;     // [384][384]
  u16t* lproj_wt= ws + 1032192;    // [384][384]
  u16t* fc1_wt  = ws + 1179648;    // [3072][768]
  u16t* fc2_wt  = ws + 3538944;    // [768][3072]
  u16t* lng  = ws + 5898240;       // 8192x384
  u16t* lnl  = ws + 9043968;       // 8192x384
  u16t* qkvg = ws + 12189696;      // 8192x1152
  u16t* qkvl = ws + 21626880;      // 8192x1152
  u16t* attg = lng;
  u16t* attl = lnl;
  u16t* x1   = ws + 12189696;      // aliases qkvg (dead by proj)
  u16t* ln2o = ws + 5898240;       // aliases lng/lnl
  u16t* hbuf = ws + 18481152;      // 8192x3072

  const int rows = B_ * N_;

  W6 w6;
  w6.w[0] = g_qkv_w;  w6.wt[0] = gqkv_wt;  w6.K[0] = 384;  w6.N[0] = 1152;
  w6.w[1] = l_qkv_w;  w6.wt[1] = lqkv_wt;  w6.K[1] = 384;  w6.N[1] = 1152;
  w6.w[2] = g_proj_w; w6.wt[2] = gproj_wt; w6.K[2] = 384;  w6.N[2] = 384;
  w6.w[3] = l_proj_w; w6.wt[3] = lproj_wt; w6.K[3] = 384;  w6.N[3] = 384;
  w6.w[4] = fc1_w;    w6.wt[4] = fc1_wt;   w6.K[4] = 768;  w6.N[4] = 3072;
  w6.w[5] = fc2_w;    w6.wt[5] = fc2_wt;   w6.K[5] = 3072; w6.N[5] = 768;
  int acc0 = 0;
  for (int i = 0; i < 6; ++i) {
    w6.start[i] = acc0;
    acc0 += (w6.N[i] / 32) * (w6.K[i] / 32);
  }
  w6.start[6] = acc0;   // 5760
  wprep_all<<<dim3(acc0), 256, 0, stream>>>(w6);

  ln1_both_k<<<dim3(2048), 256, 0, stream>>>(
      x, ln1_g, ln1_b, ln1l_g, ln1l_b, lng, lnl, rows);

  // qkv (both branches, z-merged)
  gemm_mfma<<<dim3(9, 64, 2), 256, 0, stream>>>(
      lng, lnl, 384, gqkv_wt, lqkv_wt, 384,
      nullptr, nullptr, nullptr, nullptr, 0, 0,
      qkvg, qkvl, 1152, 0, 384, 0);

  // fused attention (gattn 768 blocks + lattn 192 blocks)
  attn_both<<<dim3(960), 256, 0, stream>>>(qkvg, qkvl, attg, attl);

  // proj (both branches, z-merged), residual from x (f32), out bf16 x1
  gemm_mfma<<<dim3(3, 64, 2), 256, 0, stream>>>(
      attg, attl, 384, gproj_wt, lproj_wt, 384,
      g_proj_b, l_proj_b, x, x + 384, 768, 1,
      x1, x1 + 384, 768, 0, 384, 0);

  ln_kernel<768, u16t><<<dim3(2048), 256, 0, stream>>>(x1, 768, 0, ln2_g, ln2_b, ln2o, rows);

  gemm_mfma<<<dim3(24, 64, 1), 256, 0, stream>>>(
      ln2o, ln2o, 768, fc1_wt, fc1_wt, 768,
      fc1_b, fc1_b, nullptr, nullptr, 0, 0,
      hbuf, hbuf, 3072, 0, 768, 1);

  gemm_mfma<<<dim3(6, 64, 1), 256, 0, stream>>>(
      hbuf, hbuf, 3072, fc2_wt, fc2_wt, 3072,
      fc2_b, fc2_b, x1, x1, 768, 0,
      out, out, 768, 1, 3072, 0);
}